// Round 1
// baseline (751.789 us; speedup 1.0000x reference)
//
#include <hip/hip_runtime.h>
#include <math.h>

#define D 64
#define LPE 16          // lanes per edge
#define CPL 4           // components per lane (D / LPE)
#define MAXNORM 0.999f  // 1 - BALL_EPS
#define MIN_NORM 1e-15f
#define TANH_CLIP 15.0f

struct f4 { float x, y, z, w; };

__device__ __forceinline__ float group_sum16(float v) {
    v += __shfl_xor(v, 1);
    v += __shfl_xor(v, 2);
    v += __shfl_xor(v, 4);
    v += __shfl_xor(v, 8);
    return v;   // all 16 lanes of the group hold the sum
}

__device__ __forceinline__ float dot4(const f4& a, const f4& b) {
    return group_sum16(a.x * b.x + a.y * b.y + a.z * b.z + a.w * b.w);
}

// tanh for x >= 0, with clip at TANH_CLIP
__device__ __forceinline__ float tanh_pos(float x) {
    x = fminf(x, TANH_CLIP);
    float t = __expf(-2.0f * x);
    return (1.0f - t) / (1.0f + t);
}

// artanh for x in [0, 1-1e-7]
__device__ __forceinline__ float artanh_pos(float x) {
    x = fminf(x, 1.0f - 1e-7f);
    return 0.5f * __logf((1.0f + x) / (1.0f - x));
}

__device__ __forceinline__ f4 scale4(const f4& a, float s) {
    f4 r; r.x = a.x * s; r.y = a.y * s; r.z = a.z * s; r.w = a.w * s; return r;
}

// mobius_add(x, y) with precomputed reductions x2, y2, xy
__device__ __forceinline__ f4 mobius(const f4& x, const f4& y,
                                     float x2, float y2, float xy) {
    float a = 1.0f + 2.0f * xy + y2;   // coeff on x
    float b = 1.0f - x2;               // coeff on y
    float den = fmaxf(1.0f + 2.0f * xy + x2 * y2, MIN_NORM);
    float inv = 1.0f / den;
    f4 r;
    r.x = (a * x.x + b * y.x) * inv;
    r.y = (a * x.y + b * y.y) * inv;
    r.z = (a * x.z + b * y.z) * inv;
    r.w = (a * x.w + b * y.w) * inv;
    return r;
}

__global__ void edge_kernel(const float* __restrict__ ego,
                            const int* __restrict__ eidx,
                            const int* __restrict__ etype,
                            const float* __restrict__ rel,
                            float* __restrict__ outsum,
                            float* __restrict__ counts,
                            int E) {
    int gtid = blockIdx.x * blockDim.x + threadIdx.x;
    int e   = gtid >> 4;
    int sub = gtid & (LPE - 1);
    if (e >= E) return;

    int head = eidx[e];
    int tail = eidx[E + e];
    int type = etype[e];

    const f4 h = *(const f4*)(ego + (size_t)head * D + sub * CPL);
    const f4 t = *(const f4*)(ego + (size_t)tail * D + sub * CPL);
    const f4 r = *(const f4*)(rel + (size_t)type * D + sub * CPL);

    // hyper_head = expmap0(h)
    float nh = fmaxf(sqrtf(dot4(h, h)), MIN_NORM);
    f4 p = scale4(h, tanh_pos(nh) / nh);

    float p2  = dot4(p, p);
    float lam = 2.0f / fmaxf(1.0f - p2, MIN_NORM);

    // hyper_tail = expmap(t, p) = mobius_add(p, tanh(0.5*lam*|t|)/|t| * t)
    float nt = fmaxf(sqrtf(dot4(t, t)), MIN_NORM);
    f4 yt = scale4(t, tanh_pos(0.5f * lam * nt) / nt);
    f4 ht = mobius(p, yt, p2, dot4(yt, yt), dot4(p, yt));

    // hyper_rel = expmap(r, p)
    float nr = fmaxf(sqrtf(dot4(r, r)), MIN_NORM);
    f4 yr = scale4(r, tanh_pos(0.5f * lam * nr) / nr);
    f4 hr = mobius(p, yr, p2, dot4(yr, yr), dot4(p, yr));

    // res = project(mobius_add(ht, hr))
    f4 m = mobius(ht, hr, dot4(ht, ht), dot4(hr, hr), dot4(ht, hr));
    float nm = fmaxf(sqrtf(dot4(m, m)), MIN_NORM);
    if (nm > MAXNORM) m = scale4(m, MAXNORM / nm);

    // logmap(m, p): sub_v = mobius_add(-p, m)
    f4 npv; npv.x = -p.x; npv.y = -p.y; npv.z = -p.z; npv.w = -p.w;
    float y2l = dot4(m, m);
    float xyl = -dot4(p, m);
    f4 s = mobius(npv, m, p2, y2l, xyl);
    float ns = fmaxf(sqrtf(dot4(s, s)), MIN_NORM);
    float sc = (2.0f / lam) * artanh_pos(ns) / ns;
    f4 res = scale4(s, sc);

    float* dst = outsum + (size_t)head * D + sub * CPL;
    atomicAdd(dst + 0, res.x);
    atomicAdd(dst + 1, res.y);
    atomicAdd(dst + 2, res.z);
    atomicAdd(dst + 3, res.w);
    if (sub == 0) atomicAdd(counts + head, 1.0f);
}

__global__ void normalize_kernel(float* __restrict__ out,
                                 const float* __restrict__ counts,
                                 int n4) {
    int i = blockIdx.x * blockDim.x + threadIdx.x;
    if (i >= n4) return;
    f4 v = ((f4*)out)[i];
    float inv = 1.0f / fmaxf(counts[i >> 4], 1.0f);
    v.x *= inv; v.y *= inv; v.z *= inv; v.w *= inv;
    ((f4*)out)[i] = v;
}

extern "C" void kernel_launch(void* const* d_in, const int* in_sizes, int n_in,
                              void* d_out, int out_size, void* d_ws, size_t ws_size,
                              hipStream_t stream) {
    const float* ego  = (const float*)d_in[0];
    const int*   eidx = (const int*)d_in[1];
    const int*   etyp = (const int*)d_in[2];
    const float* rel  = (const float*)d_in[3];
    float* out = (float*)d_out;
    float* counts = (float*)d_ws;

    int E = in_sizes[1] / 2;          // 800000
    int N = in_sizes[0] / D;          // 100000

    hipMemsetAsync(d_out, 0, (size_t)out_size * sizeof(float), stream);
    hipMemsetAsync(d_ws, 0, (size_t)N * sizeof(float), stream);

    const int tpb = 256;
    long long tot = (long long)E * LPE;
    edge_kernel<<<(int)((tot + tpb - 1) / tpb), tpb, 0, stream>>>(
        ego, eidx, etyp, rel, out, counts, E);

    int n4 = N * (D / 4);
    normalize_kernel<<<(n4 + tpb - 1) / tpb, tpb, 0, stream>>>(out, counts, n4);
}

// Round 2
// 295.665 us; speedup vs baseline: 2.5427x; 2.5427x over previous
//
#include <hip/hip_runtime.h>
#include <math.h>

#define D 64
#define LPE 16          // lanes per edge
#define CPL 4           // components per lane (D / LPE)
#define MAXNORM 0.999f  // 1 - BALL_EPS
#define MIN_NORM 1e-15f
#define TANH_CLIP 15.0f
#define CHUNK 1024      // entities per scan block

struct f4 { float x, y, z, w; };

__device__ __forceinline__ float group_sum16(float v) {
    v += __shfl_xor(v, 1);
    v += __shfl_xor(v, 2);
    v += __shfl_xor(v, 4);
    v += __shfl_xor(v, 8);
    return v;   // all 16 lanes of the group hold the sum
}

__device__ __forceinline__ float dot4(const f4& a, const f4& b) {
    return group_sum16(a.x * b.x + a.y * b.y + a.z * b.z + a.w * b.w);
}

// tanh for x >= 0, with clip at TANH_CLIP
__device__ __forceinline__ float tanh_pos(float x) {
    x = fminf(x, TANH_CLIP);
    float t = __expf(-2.0f * x);
    return (1.0f - t) / (1.0f + t);
}

// artanh for x in [0, 1-1e-7]
__device__ __forceinline__ float artanh_pos(float x) {
    x = fminf(x, 1.0f - 1e-7f);
    return 0.5f * __logf((1.0f + x) / (1.0f - x));
}

__device__ __forceinline__ f4 scale4(const f4& a, float s) {
    f4 r; r.x = a.x * s; r.y = a.y * s; r.z = a.z * s; r.w = a.w * s; return r;
}

// mobius_add(x, y) with precomputed reductions x2, y2, xy
__device__ __forceinline__ f4 mobius(const f4& x, const f4& y,
                                     float x2, float y2, float xy) {
    float a = 1.0f + 2.0f * xy + y2;   // coeff on x
    float b = 1.0f - x2;               // coeff on y
    float den = fmaxf(1.0f + 2.0f * xy + x2 * y2, MIN_NORM);
    float inv = 1.0f / den;
    f4 r;
    r.x = (a * x.x + b * y.x) * inv;
    r.y = (a * x.y + b * y.y) * inv;
    r.z = (a * x.z + b * y.z) * inv;
    r.w = (a * x.w + b * y.w) * inv;
    return r;
}

// ---------------- counting sort by head ----------------

__global__ void hist_kernel(const int* __restrict__ eidx,
                            int* __restrict__ cnt, int E) {
    int e = blockIdx.x * blockDim.x + threadIdx.x;
    if (e < E) atomicAdd(&cnt[eidx[e]], 1);
}

__global__ void partial_kernel(const int* __restrict__ cnt,
                               int* __restrict__ partials, int N) {
    __shared__ int sdata[256];
    int base = blockIdx.x * CHUNK;
    int s = 0;
    for (int i = threadIdx.x; i < CHUNK; i += 256) {
        int idx = base + i;
        s += (idx < N) ? cnt[idx] : 0;
    }
    sdata[threadIdx.x] = s;
    __syncthreads();
    for (int o = 128; o > 0; o >>= 1) {
        if (threadIdx.x < o) sdata[threadIdx.x] += sdata[threadIdx.x + o];
        __syncthreads();
    }
    if (threadIdx.x == 0) partials[blockIdx.x] = sdata[0];
}

__global__ void scan_partials_kernel(int* __restrict__ partials, int nb) {
    if (blockIdx.x == 0 && threadIdx.x == 0) {
        int run = 0;
        for (int i = 0; i < nb; i++) { int v = partials[i]; partials[i] = run; run += v; }
    }
}

__global__ void scan_final_kernel(const int* __restrict__ cnt,
                                  const int* __restrict__ partials,
                                  int* __restrict__ off,
                                  int* __restrict__ cur, int N) {
    __shared__ int sdata[256];
    int tid = threadIdx.x;
    int base = blockIdx.x * CHUNK + tid * 4;
    int v0 = (base + 0 < N) ? cnt[base + 0] : 0;
    int v1 = (base + 1 < N) ? cnt[base + 1] : 0;
    int v2 = (base + 2 < N) ? cnt[base + 2] : 0;
    int v3 = (base + 3 < N) ? cnt[base + 3] : 0;
    sdata[tid] = v0 + v1 + v2 + v3;
    __syncthreads();
    for (int o = 1; o < 256; o <<= 1) {          // inclusive Hillis-Steele
        int add = (tid >= o) ? sdata[tid - o] : 0;
        __syncthreads();
        sdata[tid] += add;
        __syncthreads();
    }
    int run = partials[blockIdx.x] + ((tid > 0) ? sdata[tid - 1] : 0);
    if (base + 0 < N) { off[base + 0] = run; cur[base + 0] = run; run += v0; }
    if (base + 1 < N) { off[base + 1] = run; cur[base + 1] = run; run += v1; }
    if (base + 2 < N) { off[base + 2] = run; cur[base + 2] = run; run += v2; }
    if (base + 3 < N) { off[base + 3] = run; cur[base + 3] = run; run += v3; }
}

__global__ void scatter_kernel(const int* __restrict__ eidx,
                               int* __restrict__ cur,
                               int* __restrict__ sorted, int E) {
    int e = blockIdx.x * blockDim.x + threadIdx.x;
    if (e < E) {
        int pos = atomicAdd(&cur[eidx[e]], 1);
        sorted[pos] = e;
    }
}

// ---------------- segmented aggregation: one wave per head ----------------

__global__ void agg_kernel(const float* __restrict__ ego,
                           const int* __restrict__ eidx,
                           const int* __restrict__ etype,
                           const float* __restrict__ rel,
                           const int* __restrict__ off,
                           const int* __restrict__ cnt,
                           const int* __restrict__ sorted,
                           float* __restrict__ out,
                           int N, int E) {
    int wid = (blockIdx.x * blockDim.x + threadIdx.x) >> 6;   // one wave per head
    if (wid >= N) return;
    int lane = threadIdx.x & 63;
    int slot = lane >> 4;     // 4 parallel edge-slots
    int sub  = lane & 15;     // 16 lanes per edge, 4 comps each

    int h = wid;
    const f4 hvec = *(const f4*)(ego + (size_t)h * D + sub * CPL);

    // head-only precompute: p = expmap0(h), p2, 2/lam
    float nh = fmaxf(sqrtf(dot4(hvec, hvec)), MIN_NORM);
    f4 p = scale4(hvec, tanh_pos(nh) / nh);
    float p2 = dot4(p, p);
    float two_over_lam = fmaxf(1.0f - p2, MIN_NORM);   // = clip(1-p2)
    float half_lam = 1.0f / two_over_lam;              // 0.5 * lam

    int o = off[h];
    int c = cnt[h];
    f4 acc; acc.x = 0.f; acc.y = 0.f; acc.z = 0.f; acc.w = 0.f;

    for (int i = slot; i < c; i += 4) {
        int e = sorted[o + i];
        int tail = eidx[E + e];
        int type = etype[e];

        const f4 t = *(const f4*)(ego + (size_t)tail * D + sub * CPL);
        const f4 r = *(const f4*)(rel + (size_t)type * D + sub * CPL);

        // hyper_tail = expmap(t, p)
        float nt = fmaxf(sqrtf(dot4(t, t)), MIN_NORM);
        f4 yt = scale4(t, tanh_pos(half_lam * nt) / nt);
        f4 ht = mobius(p, yt, p2, dot4(yt, yt), dot4(p, yt));

        // hyper_rel = expmap(r, p)
        float nr = fmaxf(sqrtf(dot4(r, r)), MIN_NORM);
        f4 yr = scale4(r, tanh_pos(half_lam * nr) / nr);
        f4 hr = mobius(p, yr, p2, dot4(yr, yr), dot4(p, yr));

        // res = project(mobius_add(ht, hr))
        f4 m = mobius(ht, hr, dot4(ht, ht), dot4(hr, hr), dot4(ht, hr));
        float nm = fmaxf(sqrtf(dot4(m, m)), MIN_NORM);
        if (nm > MAXNORM) m = scale4(m, MAXNORM / nm);

        // logmap(m, p)
        f4 npv; npv.x = -p.x; npv.y = -p.y; npv.z = -p.z; npv.w = -p.w;
        float y2l = dot4(m, m);
        float xyl = -dot4(p, m);
        f4 s = mobius(npv, m, p2, y2l, xyl);
        float ns = fmaxf(sqrtf(dot4(s, s)), MIN_NORM);
        float sc = two_over_lam * artanh_pos(ns) / ns;

        acc.x += s.x * sc; acc.y += s.y * sc; acc.z += s.z * sc; acc.w += s.w * sc;
    }

    // reduce across the 4 slots (lanes l, l^16, l^32, l^48)
    acc.x += __shfl_xor(acc.x, 16); acc.x += __shfl_xor(acc.x, 32);
    acc.y += __shfl_xor(acc.y, 16); acc.y += __shfl_xor(acc.y, 32);
    acc.z += __shfl_xor(acc.z, 16); acc.z += __shfl_xor(acc.z, 32);
    acc.w += __shfl_xor(acc.w, 16); acc.w += __shfl_xor(acc.w, 32);

    if (slot == 0) {
        float invc = 1.0f / fmaxf((float)c, 1.0f);
        *(f4*)(out + (size_t)h * D + sub * CPL) = scale4(acc, invc);
    }
}

extern "C" void kernel_launch(void* const* d_in, const int* in_sizes, int n_in,
                              void* d_out, int out_size, void* d_ws, size_t ws_size,
                              hipStream_t stream) {
    const float* ego  = (const float*)d_in[0];
    const int*   eidx = (const int*)d_in[1];
    const int*   etyp = (const int*)d_in[2];
    const float* rel  = (const float*)d_in[3];
    float* out = (float*)d_out;

    int E = in_sizes[1] / 2;          // 800000
    int N = in_sizes[0] / D;          // 100000
    int NB = (N + CHUNK - 1) / CHUNK; // scan blocks

    // workspace layout (ints)
    int* cnt      = (int*)d_ws;
    int* off      = cnt + N;
    int* cur      = off + N;
    int* sorted   = cur + N;
    int* partials = sorted + E;

    hipMemsetAsync(cnt, 0, (size_t)N * sizeof(int), stream);

    const int tpb = 256;
    int egrid = (E + tpb - 1) / tpb;

    hist_kernel<<<egrid, tpb, 0, stream>>>(eidx, cnt, E);
    partial_kernel<<<NB, tpb, 0, stream>>>(cnt, partials, N);
    scan_partials_kernel<<<1, 64, 0, stream>>>(partials, NB);
    scan_final_kernel<<<NB, tpb, 0, stream>>>(cnt, partials, off, cur, N);
    scatter_kernel<<<egrid, tpb, 0, stream>>>(eidx, cur, sorted, E);

    int nwaves = N;                                   // one wave per head
    int nblocks = (nwaves + 3) / 4;                   // 4 waves per 256-block
    agg_kernel<<<nblocks, tpb, 0, stream>>>(ego, eidx, etyp, rel,
                                            off, cnt, sorted, out, N, E);
}

// Round 3
// 237.572 us; speedup vs baseline: 3.1645x; 1.2445x over previous
//
#include <hip/hip_runtime.h>
#include <math.h>

#define D 64
#define MAXNORM 0.999f
#define MAXNORM2 (0.999f * 0.999f)
#define MIN_NORM 1e-15f
#define TANH_CLIP 15.0f
#define CHUNK 1024

struct f4 { float x, y, z, w; };

__device__ __forceinline__ float frcp(float x) { return __builtin_amdgcn_rcpf(x); }
__device__ __forceinline__ float frsq(float x) { return __builtin_amdgcn_rsqf(x); }

// tanh for x >= 0 (clip at TANH_CLIP), via one v_exp + one v_rcp
__device__ __forceinline__ float tanh_pos(float x) {
    x = fminf(x, TANH_CLIP);
    float e = __expf(-2.0f * x);
    return (1.0f - e) * frcp(1.0f + e);
}

__device__ __forceinline__ float dot8p(const f4& a0, const f4& a1,
                                       const f4& b0, const f4& b1) {
    return a0.x * b0.x + a0.y * b0.y + a0.z * b0.z + a0.w * b0.w +
           a1.x * b1.x + a1.y * b1.y + a1.z * b1.z + a1.w * b1.w;
}

__device__ __forceinline__ float rsum8(float v) {
    v += __shfl_xor(v, 1);
    v += __shfl_xor(v, 2);
    v += __shfl_xor(v, 4);
    return v;
}

// ---------------- per-row norms (entities + relations fused) ----------------

__global__ void norm_kernel(const float* __restrict__ ego,
                            const float* __restrict__ rel,
                            float* __restrict__ norms,
                            float* __restrict__ relnorm, int N) {
    int wid = (blockIdx.x * blockDim.x + threadIdx.x) >> 6;
    int lane = threadIdx.x & 63;
    const float* src;
    float* dst;
    if (wid < N)            { src = ego + (size_t)wid * D;       dst = norms + wid; }
    else if (wid < N + 32)  { src = rel + (size_t)(wid - N) * D; dst = relnorm + (wid - N); }
    else return;
    float v = src[lane];
    float s = v * v;
    s += __shfl_xor(s, 1);  s += __shfl_xor(s, 2);  s += __shfl_xor(s, 4);
    s += __shfl_xor(s, 8);  s += __shfl_xor(s, 16); s += __shfl_xor(s, 32);
    if (lane == 0) *dst = sqrtf(s);
}

// ---------------- counting sort by head ----------------

__global__ void hist_kernel(const int* __restrict__ eidx,
                            int* __restrict__ cnt, int E) {
    int e = blockIdx.x * blockDim.x + threadIdx.x;
    if (e < E) atomicAdd(&cnt[eidx[e]], 1);
}

__global__ void partial_kernel(const int* __restrict__ cnt,
                               int* __restrict__ partials, int N) {
    __shared__ int sdata[256];
    int base = blockIdx.x * CHUNK;
    int s = 0;
    for (int i = threadIdx.x; i < CHUNK; i += 256) {
        int idx = base + i;
        s += (idx < N) ? cnt[idx] : 0;
    }
    sdata[threadIdx.x] = s;
    __syncthreads();
    for (int o = 128; o > 0; o >>= 1) {
        if (threadIdx.x < o) sdata[threadIdx.x] += sdata[threadIdx.x + o];
        __syncthreads();
    }
    if (threadIdx.x == 0) partials[blockIdx.x] = sdata[0];
}

__global__ void scan_partials_kernel(int* __restrict__ partials, int nb) {
    if (blockIdx.x == 0 && threadIdx.x == 0) {
        int run = 0;
        for (int i = 0; i < nb; i++) { int v = partials[i]; partials[i] = run; run += v; }
    }
}

__global__ void scan_final_kernel(const int* __restrict__ cnt,
                                  const int* __restrict__ partials,
                                  int* __restrict__ off,
                                  int* __restrict__ cur, int N) {
    __shared__ int sdata[256];
    int tid = threadIdx.x;
    int base = blockIdx.x * CHUNK + tid * 4;
    int v0 = (base + 0 < N) ? cnt[base + 0] : 0;
    int v1 = (base + 1 < N) ? cnt[base + 1] : 0;
    int v2 = (base + 2 < N) ? cnt[base + 2] : 0;
    int v3 = (base + 3 < N) ? cnt[base + 3] : 0;
    sdata[tid] = v0 + v1 + v2 + v3;
    __syncthreads();
    for (int o = 1; o < 256; o <<= 1) {
        int add = (tid >= o) ? sdata[tid - o] : 0;
        __syncthreads();
        sdata[tid] += add;
        __syncthreads();
    }
    int run = partials[blockIdx.x] + ((tid > 0) ? sdata[tid - 1] : 0);
    if (base + 0 < N) { off[base + 0] = run; cur[base + 0] = run; run += v0; }
    if (base + 1 < N) { off[base + 1] = run; cur[base + 1] = run; run += v1; }
    if (base + 2 < N) { off[base + 2] = run; cur[base + 2] = run; run += v2; }
    if (base + 3 < N) { off[base + 3] = run; cur[base + 3] = run; run += v3; }
}

__global__ void scatter_kernel(const int* __restrict__ eidx,
                               int* __restrict__ cur,
                               int* __restrict__ sorted, int E) {
    int e = blockIdx.x * blockDim.x + threadIdx.x;
    if (e < E) {
        int pos = atomicAdd(&cur[eidx[e]], 1);
        sorted[pos] = e;
    }
}

// ---------------- segmented aggregation: one wave per head ----------------
// All per-edge geometry reduced to scalar algebra over 3 dots (h.t, h.r, t.r):
// every intermediate vector is a linear combo of {p, t, r} with p = fp*h.

__global__ void __launch_bounds__(256) agg_kernel(
        const float* __restrict__ ego,
        const int* __restrict__ eidx,
        const int* __restrict__ etype,
        const float* __restrict__ rel,
        const int* __restrict__ off,
        const int* __restrict__ cnt,
        const int* __restrict__ sorted,
        const float* __restrict__ norms,
        const float* __restrict__ relnorm,
        float* __restrict__ out,
        int N, int E) {
    int wid = (blockIdx.x * blockDim.x + threadIdx.x) >> 6;   // one wave per head
    if (wid >= N) return;
    int lane = threadIdx.x & 63;
    int slot = lane >> 3;     // 8 edge-slots per wave
    int sub  = lane & 7;      // 8 lanes per edge, 8 comps each

    int h = wid;
    const float* hrow = ego + (size_t)h * D + sub * 8;
    f4 h0 = *(const f4*)(hrow);
    f4 h1 = *(const f4*)(hrow + 4);

    // head-only scalars
    float nh  = fmaxf(norms[h], MIN_NORM);
    float th  = tanh_pos(nh);
    float fp  = th * frcp(nh);                 // p = fp * h
    float p2  = th * th;
    float tol = fmaxf(1.0f - p2, MIN_NORM);    // 2/lam
    float hl  = frcp(tol);                     // 0.5*lam

    int o = off[h];
    int c = cnt[h];
    f4 a0 = {0.f, 0.f, 0.f, 0.f}, a1 = {0.f, 0.f, 0.f, 0.f};
    float accP = 0.f;

    for (int i = slot; i < c; i += 8) {
        int e    = sorted[o + i];
        int tail = eidx[E + e];
        int type = etype[e];

        const float* trow = ego + (size_t)tail * D + sub * 8;
        f4 t0 = *(const f4*)(trow);
        f4 t1 = *(const f4*)(trow + 4);
        const float* rrow = rel + (size_t)type * D + sub * 8;
        f4 r0 = *(const f4*)(rrow);
        f4 r1 = *(const f4*)(rrow + 4);
        float nt = norms[tail];
        float nr = relnorm[type];

        // the only 3 wave reductions per edge
        float d_ht = rsum8(dot8p(h0, h1, t0, t1));
        float d_hr = rsum8(dot8p(h0, h1, r0, r1));
        float d_tr = rsum8(dot8p(t0, t1, r0, r1));

        float t2 = nt * nt, r2 = nr * nr;
        float pt = fp * d_ht;                  // p.t
        float pr = fp * d_hr;                  // p.r

        // hyper_tail = mobius(p, yt), yt = ft*t
        float tt  = tanh_pos(hl * nt);
        float ft  = tt * frcp(fmaxf(nt, MIN_NORM));
        float yt2 = tt * tt;
        float pyt = ft * pt;
        float at  = 1.0f + 2.0f * pyt + yt2;
        float invt = frcp(fmaxf(1.0f + 2.0f * pyt + p2 * yt2, MIN_NORM));
        float At = at * invt;                  // coeff on p
        float Bt = tol * invt * ft;            // coeff on raw t

        // hyper_rel = mobius(p, yr), yr = fr*r
        float tr_ = tanh_pos(hl * nr);
        float fr  = tr_ * frcp(fmaxf(nr, MIN_NORM));
        float yr2 = tr_ * tr_;
        float pyr = fr * pr;
        float ar  = 1.0f + 2.0f * pyr + yr2;
        float invr = frcp(fmaxf(1.0f + 2.0f * pyr + p2 * yr2, MIN_NORM));
        float Ar = ar * invr;
        float Br = tol * invr * fr;

        // m = mobius(ht, hr) where ht = At*p+Bt*t, hr = Ar*p+Br*r
        float x2 = At * At * p2 + 2.0f * At * Bt * pt + Bt * Bt * t2;
        float y2 = Ar * Ar * p2 + 2.0f * Ar * Br * pr + Br * Br * r2;
        float xy = At * Ar * p2 + At * Br * pr + Ar * Bt * pt + Bt * Br * d_tr;
        float am = 1.0f + 2.0f * xy + y2;
        float bm = 1.0f - x2;
        float invm = frcp(fmaxf(1.0f + 2.0f * xy + x2 * y2, MIN_NORM));
        float al = (am * At + bm * Ar) * invm; // m coeff on p
        float be = am * Bt * invm;             // on t
        float ga = bm * Br * invm;             // on r

        float m2 = al * al * p2 + be * be * t2 + ga * ga * r2 +
                   2.0f * (al * be * pt + al * ga * pr + be * ga * d_tr);
        m2 = fmaxf(m2, 1e-30f);

        // project
        float scp = (m2 > MAXNORM2) ? MAXNORM * frsq(m2) : 1.0f;
        al *= scp; be *= scp; ga *= scp;
        m2 *= scp * scp;

        // s = mobius(-p, m)
        float pm   = al * p2 + be * pt + ga * pr;
        float invs = frcp(fmaxf(1.0f - 2.0f * pm + p2 * m2, MIN_NORM));
        float sp   = -(1.0f - 2.0f * pm + m2) * invs;  // s coeff on p (direct)
        float smm  = tol * invs;                       // s coeff on m
        float u = sp + smm * al;
        float v = smm * be;
        float w = smm * ga;

        float s2 = u * u * p2 + v * v * t2 + w * w * r2 +
                   2.0f * (u * v * pt + u * w * pr + v * w * d_tr);
        s2 = fmaxf(s2, 1e-30f);
        float irs = frsq(s2);
        float ns  = fminf(s2 * irs, 1.0f - 1e-7f);     // |s|, clipped for artanh
        float art = 0.5f * __logf((1.0f + ns) * frcp(1.0f - ns));
        float sc  = tol * art * irs;                   // (2/lam)*artanh(ns)/|s|

        // res = sc*(u*p + v*t + w*r); accumulate
        float ct = sc * v, cr = sc * w;
        accP += sc * u;
        a0.x += ct * t0.x + cr * r0.x;  a0.y += ct * t0.y + cr * r0.y;
        a0.z += ct * t0.z + cr * r0.z;  a0.w += ct * t0.w + cr * r0.w;
        a1.x += ct * t1.x + cr * r1.x;  a1.y += ct * t1.y + cr * r1.y;
        a1.z += ct * t1.z + cr * r1.z;  a1.w += ct * t1.w + cr * r1.w;
    }

    // reduce the 8 slots (lanes l, l^8, l^16, l^32)
    #define RED(x) x += __shfl_xor(x, 8); x += __shfl_xor(x, 16); x += __shfl_xor(x, 32);
    RED(accP)
    RED(a0.x) RED(a0.y) RED(a0.z) RED(a0.w)
    RED(a1.x) RED(a1.y) RED(a1.z) RED(a1.w)
    #undef RED

    if (slot == 0) {
        float invc = frcp(fmaxf((float)c, 1.0f));
        float hp = accP * fp * invc;               // p-coeff back to h-units
        f4 o0, o1;
        o0.x = hp * h0.x + a0.x * invc;  o0.y = hp * h0.y + a0.y * invc;
        o0.z = hp * h0.z + a0.z * invc;  o0.w = hp * h0.w + a0.w * invc;
        o1.x = hp * h1.x + a1.x * invc;  o1.y = hp * h1.y + a1.y * invc;
        o1.z = hp * h1.z + a1.z * invc;  o1.w = hp * h1.w + a1.w * invc;
        float* orow = out + (size_t)h * D + sub * 8;
        *(f4*)(orow)     = o0;
        *(f4*)(orow + 4) = o1;
    }
}

extern "C" void kernel_launch(void* const* d_in, const int* in_sizes, int n_in,
                              void* d_out, int out_size, void* d_ws, size_t ws_size,
                              hipStream_t stream) {
    const float* ego  = (const float*)d_in[0];
    const int*   eidx = (const int*)d_in[1];
    const int*   etyp = (const int*)d_in[2];
    const float* rel  = (const float*)d_in[3];
    float* out = (float*)d_out;

    int E = in_sizes[1] / 2;          // 800000
    int N = in_sizes[0] / D;          // 100000
    int NB = (N + CHUNK - 1) / CHUNK;

    // workspace layout
    int* cnt      = (int*)d_ws;           // N
    int* off      = cnt + N;              // N
    int* cur      = off + N;              // N
    int* sorted   = cur + N;              // E
    int* partials = sorted + E;           // NB
    float* norms   = (float*)(partials + NB);  // N
    float* relnorm = norms + N;                // 32

    hipMemsetAsync(cnt, 0, (size_t)N * sizeof(int), stream);

    const int tpb = 256;
    int egrid = (E + tpb - 1) / tpb;
    int nwgrid = (N + 32 + 3) / 4;        // waves for norms (4 waves/block)

    norm_kernel<<<nwgrid, tpb, 0, stream>>>(ego, rel, norms, relnorm, N);
    hist_kernel<<<egrid, tpb, 0, stream>>>(eidx, cnt, E);
    partial_kernel<<<NB, tpb, 0, stream>>>(cnt, partials, N);
    scan_partials_kernel<<<1, 64, 0, stream>>>(partials, NB);
    scan_final_kernel<<<NB, tpb, 0, stream>>>(cnt, partials, off, cur, N);
    scatter_kernel<<<egrid, tpb, 0, stream>>>(eidx, cur, sorted, E);

    int nblocks = (N + 3) / 4;            // 4 waves (heads) per 256-block
    agg_kernel<<<nblocks, tpb, 0, stream>>>(ego, eidx, etyp, rel,
                                            off, cnt, sorted, norms, relnorm,
                                            out, N, E);
}

// Round 4
// 210.130 us; speedup vs baseline: 3.5777x; 1.1306x over previous
//
#include <hip/hip_runtime.h>
#include <math.h>

#define D 64
#define MAXNORM 0.999f
#define MAXNORM2 (0.999f * 0.999f)
#define MIN_NORM 1e-15f
#define TANH_CLIP 15.0f
#define CHUNK 1024

struct f4 { float x, y, z, w; };

__device__ __forceinline__ float frcp(float x) { return __builtin_amdgcn_rcpf(x); }
__device__ __forceinline__ float frsq(float x) { return __builtin_amdgcn_rsqf(x); }

__device__ __forceinline__ float dot8p(const f4& a0, const f4& a1,
                                       const f4& b0, const f4& b1) {
    return a0.x * b0.x + a0.y * b0.y + a0.z * b0.z + a0.w * b0.w +
           a1.x * b1.x + a1.y * b1.y + a1.z * b1.z + a1.w * b1.w;
}

__device__ __forceinline__ float rsum8(float v) {
    v += __shfl_xor(v, 1);
    v += __shfl_xor(v, 2);
    v += __shfl_xor(v, 4);
    return v;
}

// ---------------- fused setup: histogram (E edges) + row norms (N+32 rows) --------

__global__ void setup_kernel(const float* __restrict__ ego,
                             const float* __restrict__ rel,
                             const int* __restrict__ eidx,
                             int* __restrict__ cnt,
                             float* __restrict__ norms,
                             float* __restrict__ relnorm,
                             int N, int E, int hist_blocks) {
    int b = blockIdx.x;
    if (b < hist_blocks) {
        int e = b * 256 + threadIdx.x;
        if (e < E) atomicAdd(&cnt[eidx[e]], 1);
        return;
    }
    int wid = (b - hist_blocks) * 4 + (threadIdx.x >> 6);
    int lane = threadIdx.x & 63;
    const float* src;
    float* dst;
    if (wid < N)            { src = ego + (size_t)wid * D;       dst = norms + wid; }
    else if (wid < N + 32)  { src = rel + (size_t)(wid - N) * D; dst = relnorm + (wid - N); }
    else return;
    float v = src[lane];
    float s = v * v;
    s += __shfl_xor(s, 1);  s += __shfl_xor(s, 2);  s += __shfl_xor(s, 4);
    s += __shfl_xor(s, 8);  s += __shfl_xor(s, 16); s += __shfl_xor(s, 32);
    if (lane == 0) *dst = sqrtf(s);
}

// ---------------- scan ----------------

__global__ void partial_kernel(const int* __restrict__ cnt,
                               int* __restrict__ partials, int N) {
    __shared__ int sdata[256];
    int base = blockIdx.x * CHUNK;
    int s = 0;
    for (int i = threadIdx.x; i < CHUNK; i += 256) {
        int idx = base + i;
        s += (idx < N) ? cnt[idx] : 0;
    }
    sdata[threadIdx.x] = s;
    __syncthreads();
    for (int o = 128; o > 0; o >>= 1) {
        if (threadIdx.x < o) sdata[threadIdx.x] += sdata[threadIdx.x + o];
        __syncthreads();
    }
    if (threadIdx.x == 0) partials[blockIdx.x] = sdata[0];
}

// one-wave parallel exclusive scan of up to 128 partials
__global__ void scan_partials_kernel(int* __restrict__ partials, int nb) {
    int lane = threadIdx.x;        // blockDim = 64
    int i0 = 2 * lane, i1 = 2 * lane + 1;
    int v0 = (i0 < nb) ? partials[i0] : 0;
    int v1 = (i1 < nb) ? partials[i1] : 0;
    int s = v0 + v1;
    for (int o = 1; o < 64; o <<= 1) {
        int u = __shfl_up(s, o);
        if (lane >= o) s += u;
    }
    int excl = s - (v0 + v1);
    if (i0 < nb) partials[i0] = excl;
    if (i1 < nb) partials[i1] = excl + v0;
}

__global__ void scan_final_kernel(const int* __restrict__ cnt,
                                  const int* __restrict__ partials,
                                  int* __restrict__ off,
                                  int* __restrict__ cur, int N) {
    __shared__ int sdata[256];
    int tid = threadIdx.x;
    int base = blockIdx.x * CHUNK + tid * 4;
    int v0 = (base + 0 < N) ? cnt[base + 0] : 0;
    int v1 = (base + 1 < N) ? cnt[base + 1] : 0;
    int v2 = (base + 2 < N) ? cnt[base + 2] : 0;
    int v3 = (base + 3 < N) ? cnt[base + 3] : 0;
    sdata[tid] = v0 + v1 + v2 + v3;
    __syncthreads();
    for (int o = 1; o < 256; o <<= 1) {
        int add = (tid >= o) ? sdata[tid - o] : 0;
        __syncthreads();
        sdata[tid] += add;
        __syncthreads();
    }
    int run = partials[blockIdx.x] + ((tid > 0) ? sdata[tid - 1] : 0);
    if (base + 0 < N) { off[base + 0] = run; cur[base + 0] = run; run += v0; }
    if (base + 1 < N) { off[base + 1] = run; cur[base + 1] = run; run += v1; }
    if (base + 2 < N) { off[base + 2] = run; cur[base + 2] = run; run += v2; }
    if (base + 3 < N) { off[base + 3] = run; cur[base + 3] = run; run += v3; }
}

// scatter packed (tail | type<<17): tail < 2^17, type < 32
__global__ void scatter_kernel(const int* __restrict__ eidx,
                               const int* __restrict__ etype,
                               int* __restrict__ cur,
                               int* __restrict__ sorted, int E) {
    int e = blockIdx.x * blockDim.x + threadIdx.x;
    if (e < E) {
        int pos = atomicAdd(&cur[eidx[e]], 1);
        sorted[pos] = eidx[E + e] | (etype[e] << 17);
    }
}

// ---------------- segmented aggregation: one wave per head ----------------
// All per-edge geometry reduced to scalar algebra over 3 dots (h.t, h.r, t.r):
// every intermediate vector is a linear combo of {p, t, r} with p = fp*h.

__global__ void __launch_bounds__(256) agg_kernel(
        const float* __restrict__ ego,
        const float* __restrict__ rel,
        const int* __restrict__ off,
        const int* __restrict__ cnt,
        const int* __restrict__ sorted,
        const float* __restrict__ norms,
        const float* __restrict__ relnorm,
        float* __restrict__ out,
        int N) {
    int wid = (blockIdx.x * blockDim.x + threadIdx.x) >> 6;   // one wave per head
    if (wid >= N) return;
    int lane = threadIdx.x & 63;
    int slot = lane >> 3;     // 8 edge-slots per wave
    int sub  = lane & 7;      // 8 lanes per edge, 8 comps each

    int h = wid;
    const float* hrow = ego + (size_t)h * D + sub * 8;
    f4 h0 = *(const f4*)(hrow);
    f4 h1 = *(const f4*)(hrow + 4);

    // head-only scalars
    float nh  = fmaxf(norms[h], MIN_NORM);
    float xh  = fminf(nh, TANH_CLIP);
    float eh  = __expf(-2.0f * xh);
    float fp  = (1.0f - eh) * frcp((1.0f + eh) * nh);   // p = fp * h
    float p2  = fp * fp * nh * nh;                      // tanh(nh)^2
    float tol = fmaxf(1.0f - p2, MIN_NORM);             // 2/lam
    float hl  = frcp(tol);                              // 0.5*lam

    int o = off[h];
    int c = cnt[h];
    f4 a0 = {0.f, 0.f, 0.f, 0.f}, a1 = {0.f, 0.f, 0.f, 0.f};
    float accP = 0.f;

    for (int i = slot; i < c; i += 8) {
        int pk   = sorted[o + i];
        int tail = pk & 0x1FFFF;
        int type = pk >> 17;

        const float* trow = ego + (size_t)tail * D + sub * 8;
        f4 t0 = *(const f4*)(trow);
        f4 t1 = *(const f4*)(trow + 4);
        const float* rrow = rel + (size_t)type * D + sub * 8;
        f4 r0 = *(const f4*)(rrow);
        f4 r1 = *(const f4*)(rrow + 4);
        float nt = norms[tail];
        float nr = relnorm[type];

        // the only 3 wave reductions per edge
        float d_ht = rsum8(dot8p(h0, h1, t0, t1));
        float d_hr = rsum8(dot8p(h0, h1, r0, r1));
        float d_tr = rsum8(dot8p(t0, t1, r0, r1));

        float t2 = nt * nt, r2 = nr * nr;
        float pt = fp * d_ht;                  // p.t
        float pr = fp * d_hr;                  // p.r

        // hyper_tail = mobius(p, yt), yt = ft*t ; ft = tanh(hl*nt)/nt (one rcp)
        float ntc = fmaxf(nt, MIN_NORM);
        float xt  = fminf(hl * ntc, TANH_CLIP);
        float et  = __expf(-2.0f * xt);
        float ft  = (1.0f - et) * frcp((1.0f + et) * ntc);
        float yt2 = ft * ft * t2;
        float pyt = ft * pt;
        float at  = 1.0f + 2.0f * pyt + yt2;
        float invt = frcp(fmaxf(1.0f + 2.0f * pyt + p2 * yt2, MIN_NORM));
        float At = at * invt;                  // coeff on p
        float Bt = tol * invt * ft;            // coeff on raw t

        // hyper_rel = mobius(p, yr), yr = fr*r
        float nrc = fmaxf(nr, MIN_NORM);
        float xr  = fminf(hl * nrc, TANH_CLIP);
        float er  = __expf(-2.0f * xr);
        float fr  = (1.0f - er) * frcp((1.0f + er) * nrc);
        float yr2 = fr * fr * r2;
        float pyr = fr * pr;
        float ar  = 1.0f + 2.0f * pyr + yr2;
        float invr = frcp(fmaxf(1.0f + 2.0f * pyr + p2 * yr2, MIN_NORM));
        float Ar = ar * invr;
        float Br = tol * invr * fr;

        // m = mobius(ht, hr) where ht = At*p+Bt*t, hr = Ar*p+Br*r
        float x2 = At * At * p2 + 2.0f * At * Bt * pt + Bt * Bt * t2;
        float y2 = Ar * Ar * p2 + 2.0f * Ar * Br * pr + Br * Br * r2;
        float xy = At * Ar * p2 + At * Br * pr + Ar * Bt * pt + Bt * Br * d_tr;
        float am = 1.0f + 2.0f * xy + y2;
        float bm = 1.0f - x2;
        float invm = frcp(fmaxf(1.0f + 2.0f * xy + x2 * y2, MIN_NORM));
        float al = (am * At + bm * Ar) * invm; // m coeff on p
        float be = am * Bt * invm;             // on t
        float ga = bm * Br * invm;             // on r

        float m2 = al * al * p2 + be * be * t2 + ga * ga * r2 +
                   2.0f * (al * be * pt + al * ga * pr + be * ga * d_tr);
        m2 = fmaxf(m2, 1e-30f);

        // project
        float scp = (m2 > MAXNORM2) ? MAXNORM * frsq(m2) : 1.0f;
        al *= scp; be *= scp; ga *= scp;
        m2 *= scp * scp;

        // s = mobius(-p, m)
        float pm   = al * p2 + be * pt + ga * pr;
        float invs = frcp(fmaxf(1.0f - 2.0f * pm + p2 * m2, MIN_NORM));
        float sp   = -(1.0f - 2.0f * pm + m2) * invs;  // s coeff on p (direct)
        float smm  = tol * invs;                       // s coeff on m
        float u = sp + smm * al;
        float v = smm * be;
        float w = smm * ga;

        float s2 = u * u * p2 + v * v * t2 + w * w * r2 +
                   2.0f * (u * v * pt + u * w * pr + v * w * d_tr);
        s2 = fmaxf(s2, 1e-30f);
        float irs = frsq(s2);
        float ns  = fminf(s2 * irs, 1.0f - 1e-7f);     // |s|, clipped for artanh
        float art = 0.5f * __logf((1.0f + ns) * frcp(1.0f - ns));
        float sc  = tol * art * irs;                   // (2/lam)*artanh(ns)/|s|

        // res = sc*(u*p + v*t + w*r); accumulate
        float ct = sc * v, cr = sc * w;
        accP += sc * u;
        a0.x += ct * t0.x + cr * r0.x;  a0.y += ct * t0.y + cr * r0.y;
        a0.z += ct * t0.z + cr * r0.z;  a0.w += ct * t0.w + cr * r0.w;
        a1.x += ct * t1.x + cr * r1.x;  a1.y += ct * t1.y + cr * r1.y;
        a1.z += ct * t1.z + cr * r1.z;  a1.w += ct * t1.w + cr * r1.w;
    }

    // reduce the 8 slots (lanes l, l^8, l^16, l^32)
    #define RED(x) x += __shfl_xor(x, 8); x += __shfl_xor(x, 16); x += __shfl_xor(x, 32);
    RED(accP)
    RED(a0.x) RED(a0.y) RED(a0.z) RED(a0.w)
    RED(a1.x) RED(a1.y) RED(a1.z) RED(a1.w)
    #undef RED

    if (slot == 0) {
        float invc = frcp(fmaxf((float)c, 1.0f));
        float hp = accP * fp * invc;               // p-coeff back to h-units
        f4 o0, o1;
        o0.x = hp * h0.x + a0.x * invc;  o0.y = hp * h0.y + a0.y * invc;
        o0.z = hp * h0.z + a0.z * invc;  o0.w = hp * h0.w + a0.w * invc;
        o1.x = hp * h1.x + a1.x * invc;  o1.y = hp * h1.y + a1.y * invc;
        o1.z = hp * h1.z + a1.z * invc;  o1.w = hp * h1.w + a1.w * invc;
        float* orow = out + (size_t)h * D + sub * 8;
        *(f4*)(orow)     = o0;
        *(f4*)(orow + 4) = o1;
    }
}

extern "C" void kernel_launch(void* const* d_in, const int* in_sizes, int n_in,
                              void* d_out, int out_size, void* d_ws, size_t ws_size,
                              hipStream_t stream) {
    const float* ego  = (const float*)d_in[0];
    const int*   eidx = (const int*)d_in[1];
    const int*   etyp = (const int*)d_in[2];
    const float* rel  = (const float*)d_in[3];
    float* out = (float*)d_out;

    int E = in_sizes[1] / 2;          // 800000
    int N = in_sizes[0] / D;          // 100000
    int NB = (N + CHUNK - 1) / CHUNK;

    // workspace layout
    int* cnt      = (int*)d_ws;           // N
    int* off      = cnt + N;              // N
    int* cur      = off + N;              // N
    int* sorted   = cur + N;              // E
    int* partials = sorted + E;           // NB
    float* norms   = (float*)(partials + NB);  // N
    float* relnorm = norms + N;                // 32

    hipMemsetAsync(cnt, 0, (size_t)N * sizeof(int), stream);

    const int tpb = 256;
    int hist_blocks = (E + tpb - 1) / tpb;
    int norm_blocks = (N + 32 + 3) / 4;

    setup_kernel<<<hist_blocks + norm_blocks, tpb, 0, stream>>>(
        ego, rel, eidx, cnt, norms, relnorm, N, E, hist_blocks);
    partial_kernel<<<NB, tpb, 0, stream>>>(cnt, partials, N);
    scan_partials_kernel<<<1, 64, 0, stream>>>(partials, NB);
    scan_final_kernel<<<NB, tpb, 0, stream>>>(cnt, partials, off, cur, N);
    scatter_kernel<<<hist_blocks, tpb, 0, stream>>>(eidx, etyp, cur, sorted, E);

    int nblocks = (N + 3) / 4;            // 4 waves (heads) per 256-block
    agg_kernel<<<nblocks, tpb, 0, stream>>>(ego, rel, off, cnt, sorted,
                                            norms, relnorm, out, N);
}